// Round 15
// baseline (260.129 us; speedup 1.0000x reference)
//
#include <hip/hip_runtime.h>
#include <hip/hip_bf16.h>
#include <stdint.h>

typedef __attribute__((ext_vector_type(4))) float f32x4;
typedef __attribute__((ext_vector_type(8))) short bf16x8;
typedef __attribute__((ext_vector_type(4))) short bf16x4;
typedef __attribute__((ext_vector_type(4))) short s16x4;

__device__ __forceinline__ float b2f(short s) {
    union { uint32_t u; float f; } v; v.u = ((uint32_t)(uint16_t)s) << 16; return v.f;
}
__device__ __forceinline__ short f2b(float f) {
    union { float f; uint32_t u; } v; v.f = f;
    uint32_t r = v.u + 0x7FFF + ((v.u >> 16) & 1);   // RNE
    return (short)(r >> 16);
}
__device__ __forceinline__ f32x4 zero4() { f32x4 z = {0.f, 0.f, 0.f, 0.f}; return z; }

__device__ __forceinline__ void async16(const void* g, void* l) {
    __builtin_amdgcn_global_load_lds(
        (const __attribute__((address_space(1))) void*)g,
        (__attribute__((address_space(3))) void*)l, 16, 0, 0);
}
__device__ __forceinline__ uint32_t lds_addr(const void* p) {
    return (uint32_t)(uintptr_t)(const __attribute__((address_space(3))) void*)p;
}
__device__ __forceinline__ float exp2fast(float x) {
    float r; asm("v_exp_f32 %0, %1" : "=v"(r) : "v"(x)); return r;
}
__device__ __forceinline__ uint32_t cvtpk(float lo, float hi) {
    uint32_t r; asm("v_cvt_pk_bf16_f32 %0, %1, %2" : "=v"(r) : "v"(lo), "v"(hi)); return r;
}

// ---------------------------------------------------------------------------
// fp32 -> bf16 conversion pre-pass (unchanged, verified).
// ---------------------------------------------------------------------------
__global__ __launch_bounds__(256)
void cvt5(const float* __restrict__ x,
          const float* __restrict__ wq, const float* __restrict__ wk,
          const float* __restrict__ wv, const float* __restrict__ wo,
          short* __restrict__ xb, short* __restrict__ wqb, short* __restrict__ wkb,
          short* __restrict__ wvb, short* __restrict__ wob)
{
    const int b = blockIdx.x;
    const float* src; short* dst; size_t off;
    if (b < 8192) { src = x; dst = xb; off = (size_t)b * 1024; }
    else {
        const int wsel = (b - 8192) >> 10;
        off = (size_t)((b - 8192) & 1023) * 1024;
        switch (wsel) {
            case 0: src = wq; dst = wqb; break;
            case 1: src = wk; dst = wkb; break;
            case 2: src = wv; dst = wvb; break;
            default: src = wo; dst = wob; break;
        }
    }
    const int t = threadIdx.x;
    const float4 v = *(const float4*)(src + off + t * 4);
    s16x4 o;
    o[0] = f2b(v.x); o[1] = f2b(v.y); o[2] = f2b(v.z); o[3] = f2b(v.w);
    *(s16x4*)(dst + off + t * 4) = o;
}

// ---------------------------------------------------------------------------
// GEMM core v2: BK=32, double-buffered, one barrier per K-step (r14, neutral
// vs r13 but kept — no harm, fewer barriers).
// ---------------------------------------------------------------------------
template <bool OUTF32, bool RESID>
__device__ __forceinline__
void gemm_core(const short* __restrict__ Ab, const short* __restrict__ Bb,
               const float* __restrict__ bias, const float* __restrict__ resid,
               void* __restrict__ Cv, int m0, int n0col, int K, int N,
               short* lsA, short* lsB)          // each 2 x 128*32 shorts
{
    const int t = threadIdx.x;
    const int wave = t >> 6, lane = t & 63;
    const int wr = wave >> 1, wc = wave & 1;
    const int lr = lane & 15, kg = lane >> 4;

    f32x4 acc[4][4];
#pragma unroll
    for (int m = 0; m < 4; ++m)
#pragma unroll
        for (int n = 0; n < 4; ++n) acc[m][n] = zero4();

    const int r0 = t >> 2;
    const int c0 = (t & 3) * 8;

    async16(Ab + (size_t)r0 * K + c0,        &lsA[t * 8]);
    async16(Ab + (size_t)(r0 + 64) * K + c0, &lsA[t * 8 + 2048]);
    async16(Bb + (size_t)r0 * K + c0,        &lsB[t * 8]);
    async16(Bb + (size_t)(r0 + 64) * K + c0, &lsB[t * 8 + 2048]);
    __syncthreads();

    int buf = 0;
    for (int k0 = 0; k0 < K; k0 += 32) {
        if (k0 + 32 < K) {
            const int kn = k0 + 32;
            short* dA = lsA + (buf ^ 1) * 4096;
            short* dB = lsB + (buf ^ 1) * 4096;
            async16(Ab + (size_t)r0 * K + kn + c0,        dA + t * 8);
            async16(Ab + (size_t)(r0 + 64) * K + kn + c0, dA + t * 8 + 2048);
            async16(Bb + (size_t)r0 * K + kn + c0,        dB + t * 8);
            async16(Bb + (size_t)(r0 + 64) * K + kn + c0, dB + t * 8 + 2048);
        }

        const short* cA = lsA + buf * 4096;
        const short* cB = lsB + buf * 4096;
        bf16x8 aF[4], bF[4];
#pragma unroll
        for (int m = 0; m < 4; ++m)
            aF[m] = *(const bf16x8*)&cA[(wr * 64 + m * 16 + lr) * 32 + kg * 8];
#pragma unroll
        for (int n = 0; n < 4; ++n)
            bF[n] = *(const bf16x8*)&cB[(wc * 64 + n * 16 + lr) * 32 + kg * 8];
#pragma unroll
        for (int m = 0; m < 4; ++m)
#pragma unroll
            for (int n = 0; n < 4; ++n)
                acc[m][n] = __builtin_amdgcn_mfma_f32_16x16x32_bf16(aF[m], bF[n], acc[m][n], 0, 0, 0);

        __syncthreads();
        buf ^= 1;
    }

#pragma unroll
    for (int n = 0; n < 4; ++n) {
        const int col = n0col + wc * 64 + n * 16 + lr;
        const float bvv = bias[col];
#pragma unroll
        for (int m = 0; m < 4; ++m) {
            const int rowb = m0 + wr * 64 + m * 16 + kg * 4;
#pragma unroll
            for (int r = 0; r < 4; ++r) {
                const size_t idx = (size_t)(rowb + r) * N + col;
                float v = acc[m][n][r] + bvv;
                if (RESID) v += resid[idx];
                if (OUTF32) ((float*)Cv)[idx] = v;
                else        ((short*)Cv)[idx] = f2b(v);
            }
        }
    }
}

// Fused QKV GEMM, 1-D grid 1536 with XCD-bijective swizzle (verified r13).
__global__ __launch_bounds__(256)
void gemm_qkv(const short* __restrict__ A, const short* __restrict__ Wcat,
              const float* __restrict__ bq, const float* __restrict__ bk,
              const float* __restrict__ bv,
              short* __restrict__ Qw, short* __restrict__ Kw, short* __restrict__ Vw)
{
    __shared__ short lsA[2 * 128 * 32];
    __shared__ short lsB[2 * 128 * 32];
    const int L = blockIdx.x;
    const int wgid = (L & 7) * 192 + (L >> 3);
    const int nb = wgid % 24;
    const int my = wgid / 24;
    const int tb = nb >> 3;
    const float* bias = (tb == 0) ? bq : (tb == 1) ? bk : bv;
    short* dst = (tb == 0) ? Qw : (tb == 1) ? Kw : Vw;
    gemm_core<false, false>(A + (size_t)my * 128 * 1024,
                            Wcat + (size_t)nb * 128 * 1024,
                            bias - (nb & 7) * 128,
                            nullptr, dst, my * 128, (nb & 7) * 128, 1024, 1024,
                            lsA, lsB);
}

// Out-projection GEMM, 1-D grid 512 with XCD-bijective swizzle (verified r13).
__global__ __launch_bounds__(256)
void gemm_out(const short* __restrict__ A, const short* __restrict__ Bw,
              const float* __restrict__ bias, const float* __restrict__ resid,
              float* __restrict__ C)
{
    __shared__ short lsA[2 * 128 * 32];
    __shared__ short lsB[2 * 128 * 32];
    const int L = blockIdx.x;
    const int wgid = (L & 7) * 64 + (L >> 3);
    const int nb = wgid & 7, my = wgid >> 3;
    gemm_core<true, true>(A + (size_t)my * 128 * 1024,
                          Bw + (size_t)nb * 128 * 1024,
                          bias, resid, C, my * 128, nb * 128, 1024, 1024,
                          lsA, lsB);
}

// ---------------------------------------------------------------------------
// MFMA flash attention v8: SPLIT-KV (2-way).  Grid (64 bh, 8 q, 2 half).
// Each half processes 1024 kv rows (16 tiles) and writes NORMALIZED partial
// O (bf16) plus per-row (m_raw, sum_p) side data.  attn_combine merges.
// Compute core identical to verified v7 (swapped QK^T, swizzled K/lsP,
// tr-read V, exp2 softmax, defer-max, ones-MFMA row-sum).
// ---------------------------------------------------------------------------
__global__ __launch_bounds__(512)
void attn_fwd(const short* __restrict__ Q, const short* __restrict__ K,
              const short* __restrict__ V, short* __restrict__ part0,
              short* __restrict__ part1, float2* __restrict__ side)
{
    __shared__ short lsK[2][64 * 64];
    __shared__ short lsV[2][64 * 64];
    __shared__ short lsP[8][16 * 64];

    const float C1 = 0.18033688011112042f;   // 0.125 * log2(e)

    const int t = threadIdx.x, w = t >> 6, lane = t & 63;
    const int lr = lane & 15, kg = lane >> 4;
    const int bh = blockIdx.x;
    const int z  = blockIdx.z;                 // kv half
    const size_t base = (size_t)(bh >> 4) * 2048 * 1024 + (size_t)(bh & 15) * 64;
    const short* Qg = Q + base;
    short* Og = (z ? part1 : part0) + base;
    const int q0 = blockIdx.y * 256 + w * 32;

    bf16x8 qB[2][2];
#pragma unroll
    for (int m = 0; m < 2; ++m)
#pragma unroll
        for (int ks = 0; ks < 2; ++ks)
            qB[m][ks] = *(const bf16x8*)(Qg + (size_t)(q0 + m * 16 + lr) * 1024 + ks * 32 + kg * 8);

    bf16x8 onesB;
#pragma unroll
    for (int j = 0; j < 8; ++j) onesB[j] = (short)0x3F80;

    const int rK  = t >> 3;
    const int cK  = (((t & 7) ^ (rK & 7))) * 8;
    const int kvV = (t & 127) >> 1;
    const int dV  = ((t >> 7) << 4) + (t & 1) * 8;
    const size_t zoff = (size_t)z << 20;       // z * 1024 rows * 1024 shorts
    const short* pK = K + base + zoff + (size_t)rK * 1024 + cK;
    const short* pV = V + base + zoff + (size_t)kvV * 1024 + dV;

    f32x4 o[2][4];
    f32x4 osum[2];
#pragma unroll
    for (int m = 0; m < 2; ++m) {
#pragma unroll
        for (int n = 0; n < 4; ++n) o[m][n] = zero4();
        osum[m] = zero4();
    }
    float mx[2] = {-1e30f, -1e30f};

    const int pmask = (lr & 7) << 3;
    short* lsPw = lsP[w];

    async16(pK, &lsK[0][t * 8]);
    async16(pV, &lsV[0][t * 8]);

    int buf = 0;
    for (int it = 0; it < 16; ++it) {
        __syncthreads();
        if (it + 1 < 16) {
            pK += 65536; pV += 65536;
            async16(pK, &lsK[buf ^ 1][t * 8]);
            async16(pV, &lsV[buf ^ 1][t * 8]);
        }
        const short* cbK = lsK[buf];
        const short* cbV = lsV[buf];

        f32x4 s[2][4];
        const int x0 = ((kg)     ^ (lr & 7)) * 8;
        const int x1 = ((4 + kg) ^ (lr & 7)) * 8;
        __builtin_amdgcn_s_setprio(1);
#pragma unroll
        for (int cb = 0; cb < 4; ++cb) {
            const bf16x8 kA0 = *(const bf16x8*)&cbK[(cb * 16 + lr) * 64 + x0];
            const bf16x8 kA1 = *(const bf16x8*)&cbK[(cb * 16 + lr) * 64 + x1];
#pragma unroll
            for (int m = 0; m < 2; ++m) {
                f32x4 a = __builtin_amdgcn_mfma_f32_16x16x32_bf16(kA0, qB[m][0], zero4(), 0, 0, 0);
                s[m][cb] = __builtin_amdgcn_mfma_f32_16x16x32_bf16(kA1, qB[m][1], a, 0, 0, 0);
            }
        }
        __builtin_amdgcn_s_setprio(0);

        float smax[2];
#pragma unroll
        for (int m = 0; m < 2; ++m) {
            float a = fmaxf(fmaxf(s[m][0][0], s[m][0][1]), fmaxf(s[m][0][2], s[m][0][3]));
            float b = fmaxf(fmaxf(s[m][1][0], s[m][1][1]), fmaxf(s[m][1][2], s[m][1][3]));
            float c = fmaxf(fmaxf(s[m][2][0], s[m][2][1]), fmaxf(s[m][2][2], s[m][2][3]));
            float d = fmaxf(fmaxf(s[m][3][0], s[m][3][1]), fmaxf(s[m][3][2], s[m][3][3]));
            float e = fmaxf(fmaxf(a, b), fmaxf(c, d));
            e = fmaxf(e, __shfl_xor(e, 16));
            e = fmaxf(e, __shfl_xor(e, 32));
            smax[m] = e;
        }

        if (!__all((smax[0] <= mx[0] + 64.f) && (smax[1] <= mx[1] + 64.f))) {
            float corrS[2];
#pragma unroll
            for (int m = 0; m < 2; ++m) {
                const float mnew = fmaxf(mx[m], smax[m]);
                corrS[m] = exp2fast((mx[m] - mnew) * C1);
                mx[m] = mnew;
            }
#pragma unroll
            for (int m = 0; m < 2; ++m) {
                f32x4 c;
#pragma unroll
                for (int r = 0; r < 4; ++r) c[r] = __shfl(corrS[m], kg * 4 + r);
#pragma unroll
                for (int n = 0; n < 4; ++n) {
                    o[m][n][0] *= c[0]; o[m][n][1] *= c[1];
                    o[m][n][2] *= c[2]; o[m][n][3] *= c[3];
                }
                osum[m][0] *= c[0]; osum[m][1] *= c[1];
                osum[m][2] *= c[2]; osum[m][3] *= c[3];
            }
        }

        bf16x4 tv[4][4];
#pragma unroll
        for (int n = 0; n < 4; ++n) {
            const uint32_t a = lds_addr(&cbV[n * 1024 + kg * 128 + lr]);
            asm volatile(
                "ds_read_b64_tr_b16 %0, %4\n\t"
                "ds_read_b64_tr_b16 %1, %4 offset:128\n\t"
                "ds_read_b64_tr_b16 %2, %4 offset:1024\n\t"
                "ds_read_b64_tr_b16 %3, %4 offset:1152"
                : "=&v"(tv[n][0]), "=&v"(tv[n][1]), "=&v"(tv[n][2]), "=&v"(tv[n][3])
                : "v"(a));
        }
        asm volatile("s_waitcnt lgkmcnt(0)" ::: "memory");
        __builtin_amdgcn_sched_barrier(0);

#pragma unroll
        for (int m = 0; m < 2; ++m) {
            const float nm2 = mx[m] * C1;
#pragma unroll
            for (int cb = 0; cb < 4; ++cb) {
                const float p0 = exp2fast(fmaf(s[m][cb][0], C1, -nm2));
                const float p1 = exp2fast(fmaf(s[m][cb][1], C1, -nm2));
                const float p2 = exp2fast(fmaf(s[m][cb][2], C1, -nm2));
                const float p3 = exp2fast(fmaf(s[m][cb][3], C1, -nm2));
                const int c0i = (cb * 16 + kg * 4) ^ pmask;
                *(uint32_t*)&lsPw[lr * 64 + c0i]     = cvtpk(p0, p1);
                *(uint32_t*)&lsPw[lr * 64 + c0i + 2] = cvtpk(p2, p3);
            }

            bf16x8 pA[2];
#pragma unroll
            for (int kh = 0; kh < 2; ++kh)
                pA[kh] = *(const bf16x8*)&lsPw[lr * 64 + ((kh * 32 + kg * 8) ^ pmask)];

            __builtin_amdgcn_s_setprio(1);
#pragma unroll
            for (int n = 0; n < 4; ++n) {
#pragma unroll
                for (int kh = 0; kh < 2; ++kh) {
                    const bf16x8 vB = __builtin_shufflevector(tv[n][kh * 2], tv[n][kh * 2 + 1],
                                                              0, 1, 2, 3, 4, 5, 6, 7);
                    o[m][n] = __builtin_amdgcn_mfma_f32_16x16x32_bf16(pA[kh], vB, o[m][n], 0, 0, 0);
                }
            }
            osum[m] = __builtin_amdgcn_mfma_f32_16x16x32_bf16(pA[0], onesB, osum[m], 0, 0, 0);
            osum[m] = __builtin_amdgcn_mfma_f32_16x16x32_bf16(pA[1], onesB, osum[m], 0, 0, 0);
            __builtin_amdgcn_s_setprio(0);
        }
        buf ^= 1;
    }

    // ---- epilogue: write normalized partial + (m, sum_p) side data
    const int head = bh & 15;
    const size_t rowg = (size_t)(bh >> 4) * 2048;
#pragma unroll
    for (int m = 0; m < 2; ++m) {
        f32x4 inv, mxr;
#pragma unroll
        for (int r = 0; r < 4; ++r) {
            inv[r] = 1.0f / osum[m][r];
            mxr[r] = __shfl(mx[m], kg * 4 + r);     // uniform shfl (all lanes)
        }
        if (lr == 0) {
#pragma unroll
            for (int r = 0; r < 4; ++r) {
                const size_t row = rowg + q0 + m * 16 + kg * 4 + r;
                side[((size_t)z * 8192 + row) * 16 + head] =
                    make_float2(mxr[r], osum[m][r]);
            }
        }
#pragma unroll
        for (int n = 0; n < 4; ++n)
#pragma unroll
            for (int r = 0; r < 4; ++r) {
                const int row = q0 + m * 16 + kg * 4 + r;
                Og[(size_t)row * 1024 + n * 16 + lr] = f2b(o[m][n][r] * inv[r]);
            }
    }
}

// ---------------------------------------------------------------------------
// Split-KV combine: ctx = a1*part0 + a2*part1, a_z ∝ exp2((m_z-M)*C1)*sum_z.
// In-place into part0 (each element read-then-written by one thread).
// ---------------------------------------------------------------------------
__global__ __launch_bounds__(256)
void attn_combine(short* __restrict__ part0, const short* __restrict__ part1,
                  const float2* __restrict__ side)
{
    const float C1 = 0.18033688011112042f;
    const int row = blockIdx.x;
    const int t = threadIdx.x;
    const int head = t >> 4;
    const float2 s1 = side[(size_t)row * 16 + head];
    const float2 s2 = side[(size_t)(8192 + row) * 16 + head];
    const float M = fmaxf(s1.x, s2.x);
    const float w1 = exp2fast((s1.x - M) * C1) * s1.y;
    const float w2 = exp2fast((s2.x - M) * C1) * s2.y;
    const float inv = 1.0f / (w1 + w2);
    const float a1 = w1 * inv, a2 = w2 * inv;
    const size_t idx = (size_t)row * 1024 + t * 4;
    s16x4 p1 = *(const s16x4*)&part0[idx];
    s16x4 p2 = *(const s16x4*)&part1[idx];
    s16x4 o;
#pragma unroll
    for (int j = 0; j < 4; ++j)
        o[j] = f2b(b2f(p1[j]) * a1 + b2f(p2[j]) * a2);
    *(s16x4*)&part0[idx] = o;
}

// ---------------------------------------------------------------------------
// In-place rowwise LayerNorm on d_out (fp32) (unchanged, verified).
// ---------------------------------------------------------------------------
__global__ __launch_bounds__(256)
void ln_inplace(float* __restrict__ io, const float* __restrict__ gamma,
                const float* __restrict__ beta)
{
    __shared__ float redS[4];
    __shared__ float redQ[4];
    const int t = threadIdx.x, wave = t >> 6, lane = t & 63;
    const size_t rb = (size_t)blockIdx.x * 1024;

    float4 v4 = *(const float4*)&io[rb + t * 4];
    float v[4] = {v4.x, v4.y, v4.z, v4.w};

    float s = 0.f, sq = 0.f;
#pragma unroll
    for (int j = 0; j < 4; ++j) { s += v[j]; sq += v[j] * v[j]; }
#pragma unroll
    for (int off = 32; off; off >>= 1) {
        s  += __shfl_xor(s, off);
        sq += __shfl_xor(sq, off);
    }
    if (lane == 0) { redS[wave] = s; redQ[wave] = sq; }
    __syncthreads();
    const float mean = (redS[0] + redS[1] + redS[2] + redS[3]) * (1.0f / 1024.0f);
    const float ex2  = (redQ[0] + redQ[1] + redQ[2] + redQ[3]) * (1.0f / 1024.0f);
    const float var  = fmaxf(ex2 - mean * mean, 0.f);
    const float inv  = rsqrtf(var + 1e-5f);

    float4 o4;
    o4.x = (v[0] - mean) * inv * gamma[t * 4 + 0] + beta[t * 4 + 0];
    o4.y = (v[1] - mean) * inv * gamma[t * 4 + 1] + beta[t * 4 + 1];
    o4.z = (v[2] - mean) * inv * gamma[t * 4 + 2] + beta[t * 4 + 2];
    o4.w = (v[3] - mean) * inv * gamma[t * 4 + 3] + beta[t * 4 + 3];
    *(float4*)&io[rb + t * 4] = o4;
}

// ---------------------------------------------------------------------------
extern "C" void kernel_launch(void* const* d_in, const int* in_sizes, int n_in,
                              void* d_out, int out_size, void* d_ws, size_t ws_size,
                              hipStream_t stream)
{
    const float* x  = (const float*)d_in[0];
    const float* Wq = (const float*)d_in[1];
    const float* bq = (const float*)d_in[2];
    const float* Wk = (const float*)d_in[3];
    const float* bk = (const float*)d_in[4];
    const float* Wv = (const float*)d_in[5];
    const float* bv = (const float*)d_in[6];
    const float* Wo = (const float*)d_in[7];
    const float* bo = (const float*)d_in[8];
    const float* gamma = (const float*)d_in[9];
    const float* beta  = (const float*)d_in[10];

    const size_t NX = (size_t)8192 * 1024;
    const size_t NW = (size_t)1024 * 1024;

    short* xb  = (short*)d_ws;     // reused as part1 after gemm_qkv
    short* Wqb = xb + NX;          // [Wq;Wk;Wv] contiguous; reused as side after gemm_qkv
    short* Wkb = Wqb + NW;
    short* Wvb = Wkb + NW;
    short* Wob = Wvb + NW;
    short* Qw  = Wob + NW;
    short* Kw  = Qw + NX;
    short* Vw  = Kw + NX;
    short* Cw  = Vw + NX;          // part0 / final ctx
    float* out = (float*)d_out;

    short*  part1 = xb;
    float2* side  = (float2*)Wqb;  // 2 MB, exact fit in Wqb's region

    cvt5<<<dim3(12288), dim3(256), 0, stream>>>(x, Wq, Wk, Wv, Wo, xb, Wqb, Wkb, Wvb, Wob);
    gemm_qkv<<<dim3(1536), dim3(256), 0, stream>>>(xb, Wqb, bq, bk, bv, Qw, Kw, Vw);
    attn_fwd<<<dim3(64, 8, 2), dim3(512), 0, stream>>>(Qw, Kw, Vw, Cw, part1, side);
    attn_combine<<<dim3(8192), dim3(256), 0, stream>>>(Cw, part1, side);
    gemm_out<<<dim3(512), dim3(256), 0, stream>>>(Cw, Wob, bo, x, out);
    ln_inplace<<<dim3(8192), dim3(256), 0, stream>>>(out, gamma, beta);
}

// Round 16
// 233.179 us; speedup vs baseline: 1.1156x; 1.1156x over previous
//
#include <hip/hip_runtime.h>
#include <hip/hip_bf16.h>
#include <stdint.h>

typedef __attribute__((ext_vector_type(4))) float f32x4;
typedef __attribute__((ext_vector_type(8))) short bf16x8;
typedef __attribute__((ext_vector_type(4))) short bf16x4;
typedef __attribute__((ext_vector_type(4))) short s16x4;

__device__ __forceinline__ float b2f(short s) {
    union { uint32_t u; float f; } v; v.u = ((uint32_t)(uint16_t)s) << 16; return v.f;
}
__device__ __forceinline__ short f2b(float f) {
    union { float f; uint32_t u; } v; v.f = f;
    uint32_t r = v.u + 0x7FFF + ((v.u >> 16) & 1);   // RNE
    return (short)(r >> 16);
}
__device__ __forceinline__ f32x4 zero4() { f32x4 z = {0.f, 0.f, 0.f, 0.f}; return z; }

__device__ __forceinline__ void async16(const void* g, void* l) {
    __builtin_amdgcn_global_load_lds(
        (const __attribute__((address_space(1))) void*)g,
        (__attribute__((address_space(3))) void*)l, 16, 0, 0);
}
__device__ __forceinline__ uint32_t lds_addr(const void* p) {
    return (uint32_t)(uintptr_t)(const __attribute__((address_space(3))) void*)p;
}
__device__ __forceinline__ float exp2fast(float x) {
    float r; asm("v_exp_f32 %0, %1" : "=v"(r) : "v"(x)); return r;
}
__device__ __forceinline__ uint32_t cvtpk(float lo, float hi) {
    uint32_t r; asm("v_cvt_pk_bf16_f32 %0, %1, %2" : "=v"(r) : "v"(lo), "v"(hi)); return r;
}

// ---------------------------------------------------------------------------
// fp32 -> bf16 conversion pre-pass (unchanged, verified).
// ---------------------------------------------------------------------------
__global__ __launch_bounds__(256)
void cvt5(const float* __restrict__ x,
          const float* __restrict__ wq, const float* __restrict__ wk,
          const float* __restrict__ wv, const float* __restrict__ wo,
          short* __restrict__ xb, short* __restrict__ wqb, short* __restrict__ wkb,
          short* __restrict__ wvb, short* __restrict__ wob)
{
    const int b = blockIdx.x;
    const float* src; short* dst; size_t off;
    if (b < 8192) { src = x; dst = xb; off = (size_t)b * 1024; }
    else {
        const int wsel = (b - 8192) >> 10;
        off = (size_t)((b - 8192) & 1023) * 1024;
        switch (wsel) {
            case 0: src = wq; dst = wqb; break;
            case 1: src = wk; dst = wkb; break;
            case 2: src = wv; dst = wvb; break;
            default: src = wo; dst = wob; break;
        }
    }
    const int t = threadIdx.x;
    const float4 v = *(const float4*)(src + off + t * 4);
    s16x4 o;
    o[0] = f2b(v.x); o[1] = f2b(v.y); o[2] = f2b(v.z); o[3] = f2b(v.w);
    *(s16x4*)(dst + off + t * 4) = o;
}

// ---------------------------------------------------------------------------
// GEMM core, BK=64 (round-13 best-measured version).
// ---------------------------------------------------------------------------
template <bool OUTF32, bool RESID>
__device__ __forceinline__
void gemm_core(const short* __restrict__ Ab, const short* __restrict__ Bb,
               const float* __restrict__ bias, const float* __restrict__ resid,
               void* __restrict__ Cv, int m0, int n0col, int K, int N,
               short* lsA, short* lsB)
{
    const int t = threadIdx.x;
    const int wave = t >> 6, lane = t & 63;
    const int wr = wave >> 1, wc = wave & 1;
    const int lr = lane & 15, kg = lane >> 4;

    f32x4 acc[4][4];
#pragma unroll
    for (int m = 0; m < 4; ++m)
#pragma unroll
        for (int n = 0; n < 4; ++n) acc[m][n] = zero4();

    const int rG = t >> 3;
    const int cG = (((t & 7) ^ (rG & 7))) * 8;

    for (int k0 = 0; k0 < K; k0 += 64) {
        __syncthreads();
#pragma unroll
        for (int i = 0; i < 4; ++i) {
            async16(Ab + (size_t)(rG + 32 * i) * K + k0 + cG, &lsA[t * 8 + 2048 * i]);
            async16(Bb + (size_t)(rG + 32 * i) * K + k0 + cG, &lsB[t * 8 + 2048 * i]);
        }
        __syncthreads();

#pragma unroll
        for (int ks = 0; ks < 2; ++ks) {
            const int xc = ((ks * 4 + kg) ^ (lr & 7)) * 8;
            bf16x8 aF[4], bF[4];
#pragma unroll
            for (int m = 0; m < 4; ++m)
                aF[m] = *(const bf16x8*)&lsA[(wr * 64 + m * 16 + lr) * 64 + xc];
#pragma unroll
            for (int n = 0; n < 4; ++n)
                bF[n] = *(const bf16x8*)&lsB[(wc * 64 + n * 16 + lr) * 64 + xc];
#pragma unroll
            for (int m = 0; m < 4; ++m)
#pragma unroll
                for (int n = 0; n < 4; ++n)
                    acc[m][n] = __builtin_amdgcn_mfma_f32_16x16x32_bf16(aF[m], bF[n], acc[m][n], 0, 0, 0);
        }
    }

#pragma unroll
    for (int n = 0; n < 4; ++n) {
        const int col = n0col + wc * 64 + n * 16 + lr;
        const float bvv = bias[col];
#pragma unroll
        for (int m = 0; m < 4; ++m) {
            const int rowb = m0 + wr * 64 + m * 16 + kg * 4;
#pragma unroll
            for (int r = 0; r < 4; ++r) {
                const size_t idx = (size_t)(rowb + r) * N + col;
                float v = acc[m][n][r] + bvv;
                if (RESID) v += resid[idx];
                if (OUTF32) ((float*)Cv)[idx] = v;
                else        ((short*)Cv)[idx] = f2b(v);
            }
        }
    }
}

// Fused QKV GEMM, 1-D grid 1536 with XCD-bijective swizzle (verified r13).
__global__ __launch_bounds__(256)
void gemm_qkv(const short* __restrict__ A, const short* __restrict__ Wcat,
              const float* __restrict__ bq, const float* __restrict__ bk,
              const float* __restrict__ bv,
              short* __restrict__ Qw, short* __restrict__ Kw, short* __restrict__ Vw)
{
    __shared__ short lsA[128 * 64];
    __shared__ short lsB[128 * 64];
    const int L = blockIdx.x;                       // 0..1535
    const int wgid = (L & 7) * 192 + (L >> 3);      // bijective (1536 % 8 == 0)
    const int nb = wgid % 24;
    const int my = wgid / 24;
    const int tb = nb >> 3;
    const float* bias = (tb == 0) ? bq : (tb == 1) ? bk : bv;
    short* dst = (tb == 0) ? Qw : (tb == 1) ? Kw : Vw;
    gemm_core<false, false>(A + (size_t)my * 128 * 1024,
                            Wcat + (size_t)nb * 128 * 1024,
                            bias - (nb & 7) * 128,
                            nullptr, dst, my * 128, (nb & 7) * 128, 1024, 1024,
                            lsA, lsB);
}

// Out-projection GEMM, 1-D grid 512 with XCD-bijective swizzle (verified r13).
__global__ __launch_bounds__(256)
void gemm_out(const short* __restrict__ A, const short* __restrict__ Bw,
              const float* __restrict__ bias, const float* __restrict__ resid,
              float* __restrict__ C)
{
    __shared__ short lsA[128 * 64];
    __shared__ short lsB[128 * 64];
    const int L = blockIdx.x;                       // 0..511
    const int wgid = (L & 7) * 64 + (L >> 3);
    const int nb = wgid & 7, my = wgid >> 3;
    gemm_core<true, true>(A + (size_t)my * 128 * 1024,
                          Bw + (size_t)nb * 128 * 1024,
                          bias, resid, C, my * 128, nb * 128, 1024, 1024,
                          lsA, lsB);
}

// ---------------------------------------------------------------------------
// MFMA flash attention v9 = verified v7 (full-KV, ones-MFMA row-sum) with
// one reorder: V tr-reads issued immediately after QK^T so their ~120cy
// latency overlaps the serial softmax chain; the lgkmcnt(0)+sched_barrier(0)
// fence stays immediately before the consuming PV phase (rule #18).
// ---------------------------------------------------------------------------
__global__ __launch_bounds__(512)
void attn_fwd(const short* __restrict__ Q, const short* __restrict__ K,
              const short* __restrict__ V, short* __restrict__ ctx)
{
    __shared__ short lsK[2][64 * 64];
    __shared__ short lsV[2][64 * 64];
    __shared__ short lsP[8][16 * 64];

    const float C1 = 0.18033688011112042f;   // 0.125 * log2(e)

    const int t = threadIdx.x, w = t >> 6, lane = t & 63;
    const int lr = lane & 15, kg = lane >> 4;
    const int bh = blockIdx.x;
    const size_t base = (size_t)(bh >> 4) * 2048 * 1024 + (size_t)(bh & 15) * 64;
    const short* Qg = Q + base;
    short* Og = ctx + base;
    const int q0 = blockIdx.y * 256 + w * 32;

    bf16x8 qB[2][2];
#pragma unroll
    for (int m = 0; m < 2; ++m)
#pragma unroll
        for (int ks = 0; ks < 2; ++ks)
            qB[m][ks] = *(const bf16x8*)(Qg + (size_t)(q0 + m * 16 + lr) * 1024 + ks * 32 + kg * 8);

    bf16x8 onesB;
#pragma unroll
    for (int j = 0; j < 8; ++j) onesB[j] = (short)0x3F80;

    const int rK  = t >> 3;
    const int cK  = (((t & 7) ^ (rK & 7))) * 8;
    const int kvV = (t & 127) >> 1;
    const int dV  = ((t >> 7) << 4) + (t & 1) * 8;
    const short* pK = K + base + (size_t)rK * 1024 + cK;
    const short* pV = V + base + (size_t)kvV * 1024 + dV;

    f32x4 o[2][4];
    f32x4 osum[2];
#pragma unroll
    for (int m = 0; m < 2; ++m) {
#pragma unroll
        for (int n = 0; n < 4; ++n) o[m][n] = zero4();
        osum[m] = zero4();
    }
    float mx[2] = {-1e30f, -1e30f};

    const int pmask = (lr & 7) << 3;
    short* lsPw = lsP[w];

    async16(pK, &lsK[0][t * 8]);
    async16(pV, &lsV[0][t * 8]);

    int buf = 0;
    for (int it = 0; it < 32; ++it) {
        __syncthreads();
        if (it + 1 < 32) {
            pK += 65536; pV += 65536;
            async16(pK, &lsK[buf ^ 1][t * 8]);
            async16(pV, &lsV[buf ^ 1][t * 8]);
        }
        const short* cbK = lsK[buf];
        const short* cbV = lsV[buf];

        // ---- QK^T (swapped): s[m][cb][r] = S[q=m*16+lr][kv=cb*16+kg*4+r]
        f32x4 s[2][4];
        const int x0 = ((kg)     ^ (lr & 7)) * 8;
        const int x1 = ((4 + kg) ^ (lr & 7)) * 8;
        __builtin_amdgcn_s_setprio(1);
#pragma unroll
        for (int cb = 0; cb < 4; ++cb) {
            const bf16x8 kA0 = *(const bf16x8*)&cbK[(cb * 16 + lr) * 64 + x0];
            const bf16x8 kA1 = *(const bf16x8*)&cbK[(cb * 16 + lr) * 64 + x1];
#pragma unroll
            for (int m = 0; m < 2; ++m) {
                f32x4 a = __builtin_amdgcn_mfma_f32_16x16x32_bf16(kA0, qB[m][0], zero4(), 0, 0, 0);
                s[m][cb] = __builtin_amdgcn_mfma_f32_16x16x32_bf16(kA1, qB[m][1], a, 0, 0, 0);
            }
        }
        __builtin_amdgcn_s_setprio(0);

        // ---- V tr-reads issued EARLY: latency overlaps the softmax chain
        bf16x4 tv[4][4];
#pragma unroll
        for (int n = 0; n < 4; ++n) {
            const uint32_t a = lds_addr(&cbV[n * 1024 + kg * 128 + lr]);
            asm volatile(
                "ds_read_b64_tr_b16 %0, %4\n\t"
                "ds_read_b64_tr_b16 %1, %4 offset:128\n\t"
                "ds_read_b64_tr_b16 %2, %4 offset:1024\n\t"
                "ds_read_b64_tr_b16 %3, %4 offset:1152"
                : "=&v"(tv[n][0]), "=&v"(tv[n][1]), "=&v"(tv[n][2]), "=&v"(tv[n][3])
                : "v"(a));
        }

        // ---- tile max per q-row
        float smax[2];
#pragma unroll
        for (int m = 0; m < 2; ++m) {
            float a = fmaxf(fmaxf(s[m][0][0], s[m][0][1]), fmaxf(s[m][0][2], s[m][0][3]));
            float b = fmaxf(fmaxf(s[m][1][0], s[m][1][1]), fmaxf(s[m][1][2], s[m][1][3]));
            float c = fmaxf(fmaxf(s[m][2][0], s[m][2][1]), fmaxf(s[m][2][2], s[m][2][3]));
            float d = fmaxf(fmaxf(s[m][3][0], s[m][3][1]), fmaxf(s[m][3][2], s[m][3][3]));
            float e = fmaxf(fmaxf(a, b), fmaxf(c, d));
            e = fmaxf(e, __shfl_xor(e, 16));
            e = fmaxf(e, __shfl_xor(e, 32));
            smax[m] = e;
        }

        // ---- defer-max rescale (osum rescales with o; rare after warmup)
        if (!__all((smax[0] <= mx[0] + 64.f) && (smax[1] <= mx[1] + 64.f))) {
            float corrS[2];
#pragma unroll
            for (int m = 0; m < 2; ++m) {
                const float mnew = fmaxf(mx[m], smax[m]);
                corrS[m] = exp2fast((mx[m] - mnew) * C1);
                mx[m] = mnew;
            }
#pragma unroll
            for (int m = 0; m < 2; ++m) {
                f32x4 c;
#pragma unroll
                for (int r = 0; r < 4; ++r) c[r] = __shfl(corrS[m], kg * 4 + r);
#pragma unroll
                for (int n = 0; n < 4; ++n) {
                    o[m][n][0] *= c[0]; o[m][n][1] *= c[1];
                    o[m][n][2] *= c[2]; o[m][n][3] *= c[3];
                }
                osum[m][0] *= c[0]; osum[m][1] *= c[1];
                osum[m][2] *= c[2]; osum[m][3] *= c[3];
            }
        }

        // ---- fence for the early tr-reads, right before their consumers
        asm volatile("s_waitcnt lgkmcnt(0)" ::: "memory");
        __builtin_amdgcn_sched_barrier(0);

        // ---- per-m phases: pack P -> swizzled lsP -> pA -> PV + ones-sum
#pragma unroll
        for (int m = 0; m < 2; ++m) {
            const float nm2 = mx[m] * C1;
#pragma unroll
            for (int cb = 0; cb < 4; ++cb) {
                const float p0 = exp2fast(fmaf(s[m][cb][0], C1, -nm2));
                const float p1 = exp2fast(fmaf(s[m][cb][1], C1, -nm2));
                const float p2 = exp2fast(fmaf(s[m][cb][2], C1, -nm2));
                const float p3 = exp2fast(fmaf(s[m][cb][3], C1, -nm2));
                const int c0i = (cb * 16 + kg * 4) ^ pmask;
                *(uint32_t*)&lsPw[lr * 64 + c0i]     = cvtpk(p0, p1);
                *(uint32_t*)&lsPw[lr * 64 + c0i + 2] = cvtpk(p2, p3);
            }

            bf16x8 pA[2];
#pragma unroll
            for (int kh = 0; kh < 2; ++kh)
                pA[kh] = *(const bf16x8*)&lsPw[lr * 64 + ((kh * 32 + kg * 8) ^ pmask)];

            __builtin_amdgcn_s_setprio(1);
#pragma unroll
            for (int n = 0; n < 4; ++n) {
#pragma unroll
                for (int kh = 0; kh < 2; ++kh) {
                    const bf16x8 vB = __builtin_shufflevector(tv[n][kh * 2], tv[n][kh * 2 + 1],
                                                              0, 1, 2, 3, 4, 5, 6, 7);
                    o[m][n] = __builtin_amdgcn_mfma_f32_16x16x32_bf16(pA[kh], vB, o[m][n], 0, 0, 0);
                }
            }
            osum[m] = __builtin_amdgcn_mfma_f32_16x16x32_bf16(pA[0], onesB, osum[m], 0, 0, 0);
            osum[m] = __builtin_amdgcn_mfma_f32_16x16x32_bf16(pA[1], onesB, osum[m], 0, 0, 0);
            __builtin_amdgcn_s_setprio(0);
        }
        buf ^= 1;
    }

    // ---- epilogue: normalize; osum layout matches output rows exactly
#pragma unroll
    for (int m = 0; m < 2; ++m) {
        f32x4 inv;
#pragma unroll
        for (int r = 0; r < 4; ++r) inv[r] = 1.0f / osum[m][r];
#pragma unroll
        for (int n = 0; n < 4; ++n)
#pragma unroll
            for (int r = 0; r < 4; ++r) {
                const int row = q0 + m * 16 + kg * 4 + r;
                Og[(size_t)row * 1024 + n * 16 + lr] = f2b(o[m][n][r] * inv[r]);
            }
    }
}

// ---------------------------------------------------------------------------
// In-place rowwise LayerNorm on d_out (fp32) (unchanged, verified).
// ---------------------------------------------------------------------------
__global__ __launch_bounds__(256)
void ln_inplace(float* __restrict__ io, const float* __restrict__ gamma,
                const float* __restrict__ beta)
{
    __shared__ float redS[4];
    __shared__ float redQ[4];
    const int t = threadIdx.x, wave = t >> 6, lane = t & 63;
    const size_t rb = (size_t)blockIdx.x * 1024;

    float4 v4 = *(const float4*)&io[rb + t * 4];
    float v[4] = {v4.x, v4.y, v4.z, v4.w};

    float s = 0.f, sq = 0.f;
#pragma unroll
    for (int j = 0; j < 4; ++j) { s += v[j]; sq += v[j] * v[j]; }
#pragma unroll
    for (int off = 32; off; off >>= 1) {
        s  += __shfl_xor(s, off);
        sq += __shfl_xor(sq, off);
    }
    if (lane == 0) { redS[wave] = s; redQ[wave] = sq; }
    __syncthreads();
    const float mean = (redS[0] + redS[1] + redS[2] + redS[3]) * (1.0f / 1024.0f);
    const float ex2  = (redQ[0] + redQ[1] + redQ[2] + redQ[3]) * (1.0f / 1024.0f);
    const float var  = fmaxf(ex2 - mean * mean, 0.f);
    const float inv  = rsqrtf(var + 1e-5f);

    float4 o4;
    o4.x = (v[0] - mean) * inv * gamma[t * 4 + 0] + beta[t * 4 + 0];
    o4.y = (v[1] - mean) * inv * gamma[t * 4 + 1] + beta[t * 4 + 1];
    o4.z = (v[2] - mean) * inv * gamma[t * 4 + 2] + beta[t * 4 + 2];
    o4.w = (v[3] - mean) * inv * gamma[t * 4 + 3] + beta[t * 4 + 3];
    *(float4*)&io[rb + t * 4] = o4;
}

// ---------------------------------------------------------------------------
extern "C" void kernel_launch(void* const* d_in, const int* in_sizes, int n_in,
                              void* d_out, int out_size, void* d_ws, size_t ws_size,
                              hipStream_t stream)
{
    const float* x  = (const float*)d_in[0];
    const float* Wq = (const float*)d_in[1];
    const float* bq = (const float*)d_in[2];
    const float* Wk = (const float*)d_in[3];
    const float* bk = (const float*)d_in[4];
    const float* Wv = (const float*)d_in[5];
    const float* bv = (const float*)d_in[6];
    const float* Wo = (const float*)d_in[7];
    const float* bo = (const float*)d_in[8];
    const float* gamma = (const float*)d_in[9];
    const float* beta  = (const float*)d_in[10];

    const size_t NX = (size_t)8192 * 1024;
    const size_t NW = (size_t)1024 * 1024;

    short* xb  = (short*)d_ws;
    short* Wqb = xb + NX;          // [Wq;Wk;Wv] contiguous for fused GEMM
    short* Wkb = Wqb + NW;
    short* Wvb = Wkb + NW;
    short* Wob = Wvb + NW;
    short* Qw  = Wob + NW;
    short* Kw  = Qw + NX;
    short* Vw  = Kw + NX;
    short* Cw  = Vw + NX;
    float* out = (float*)d_out;

    cvt5<<<dim3(12288), dim3(256), 0, stream>>>(x, Wq, Wk, Wv, Wo, xb, Wqb, Wkb, Wvb, Wob);
    gemm_qkv<<<dim3(1536), dim3(256), 0, stream>>>(xb, Wqb, bq, bk, bv, Qw, Kw, Vw);
    attn_fwd<<<dim3(64, 8), dim3(512), 0, stream>>>(Qw, Kw, Vw, Cw);
    gemm_out<<<dim3(512), dim3(256), 0, stream>>>(Cw, Wob, bo, x, out);
    ln_inplace<<<dim3(8192), dim3(256), 0, stream>>>(out, gamma, beta);
}

// Round 17
// 229.375 us; speedup vs baseline: 1.1341x; 1.0166x over previous
//
#include <hip/hip_runtime.h>
#include <hip/hip_bf16.h>
#include <stdint.h>

typedef __attribute__((ext_vector_type(4))) float f32x4;
typedef __attribute__((ext_vector_type(8))) short bf16x8;
typedef __attribute__((ext_vector_type(4))) short bf16x4;
typedef __attribute__((ext_vector_type(4))) short s16x4;

__device__ __forceinline__ float b2f(short s) {
    union { uint32_t u; float f; } v; v.u = ((uint32_t)(uint16_t)s) << 16; return v.f;
}
__device__ __forceinline__ short f2b(float f) {
    union { float f; uint32_t u; } v; v.f = f;
    uint32_t r = v.u + 0x7FFF + ((v.u >> 16) & 1);   // RNE
    return (short)(r >> 16);
}
__device__ __forceinline__ f32x4 zero4() { f32x4 z = {0.f, 0.f, 0.f, 0.f}; return z; }

__device__ __forceinline__ void async16(const void* g, void* l) {
    __builtin_amdgcn_global_load_lds(
        (const __attribute__((address_space(1))) void*)g,
        (__attribute__((address_space(3))) void*)l, 16, 0, 0);
}
__device__ __forceinline__ uint32_t lds_addr(const void* p) {
    return (uint32_t)(uintptr_t)(const __attribute__((address_space(3))) void*)p;
}
__device__ __forceinline__ float exp2fast(float x) {
    float r; asm("v_exp_f32 %0, %1" : "=v"(r) : "v"(x)); return r;
}
__device__ __forceinline__ uint32_t cvtpk(float lo, float hi) {
    uint32_t r; asm("v_cvt_pk_bf16_f32 %0, %1, %2" : "=v"(r) : "v"(lo), "v"(hi)); return r;
}
__device__ __forceinline__ float max3f(float a, float b, float c) {
    float r; asm("v_max3_f32 %0, %1, %2, %3" : "=v"(r) : "v"(a), "v"(b), "v"(c)); return r;
}

// ---------------------------------------------------------------------------
// fp32 -> bf16 conversion pre-pass (unchanged, verified).
// ---------------------------------------------------------------------------
__global__ __launch_bounds__(256)
void cvt5(const float* __restrict__ x,
          const float* __restrict__ wq, const float* __restrict__ wk,
          const float* __restrict__ wv, const float* __restrict__ wo,
          short* __restrict__ xb, short* __restrict__ wqb, short* __restrict__ wkb,
          short* __restrict__ wvb, short* __restrict__ wob)
{
    const int b = blockIdx.x;
    const float* src; short* dst; size_t off;
    if (b < 8192) { src = x; dst = xb; off = (size_t)b * 1024; }
    else {
        const int wsel = (b - 8192) >> 10;
        off = (size_t)((b - 8192) & 1023) * 1024;
        switch (wsel) {
            case 0: src = wq; dst = wqb; break;
            case 1: src = wk; dst = wkb; break;
            case 2: src = wv; dst = wvb; break;
            default: src = wo; dst = wob; break;
        }
    }
    const int t = threadIdx.x;
    const float4 v = *(const float4*)(src + off + t * 4);
    s16x4 o;
    o[0] = f2b(v.x); o[1] = f2b(v.y); o[2] = f2b(v.z); o[3] = f2b(v.w);
    *(s16x4*)(dst + off + t * 4) = o;
}

// ---------------------------------------------------------------------------
// GEMM core, BK=64 (round-13 best-measured version, unchanged).
// ---------------------------------------------------------------------------
template <bool OUTF32, bool RESID>
__device__ __forceinline__
void gemm_core(const short* __restrict__ Ab, const short* __restrict__ Bb,
               const float* __restrict__ bias, const float* __restrict__ resid,
               void* __restrict__ Cv, int m0, int n0col, int K, int N,
               short* lsA, short* lsB)
{
    const int t = threadIdx.x;
    const int wave = t >> 6, lane = t & 63;
    const int wr = wave >> 1, wc = wave & 1;
    const int lr = lane & 15, kg = lane >> 4;

    f32x4 acc[4][4];
#pragma unroll
    for (int m = 0; m < 4; ++m)
#pragma unroll
        for (int n = 0; n < 4; ++n) acc[m][n] = zero4();

    const int rG = t >> 3;
    const int cG = (((t & 7) ^ (rG & 7))) * 8;

    for (int k0 = 0; k0 < K; k0 += 64) {
        __syncthreads();
#pragma unroll
        for (int i = 0; i < 4; ++i) {
            async16(Ab + (size_t)(rG + 32 * i) * K + k0 + cG, &lsA[t * 8 + 2048 * i]);
            async16(Bb + (size_t)(rG + 32 * i) * K + k0 + cG, &lsB[t * 8 + 2048 * i]);
        }
        __syncthreads();

#pragma unroll
        for (int ks = 0; ks < 2; ++ks) {
            const int xc = ((ks * 4 + kg) ^ (lr & 7)) * 8;
            bf16x8 aF[4], bF[4];
#pragma unroll
            for (int m = 0; m < 4; ++m)
                aF[m] = *(const bf16x8*)&lsA[(wr * 64 + m * 16 + lr) * 64 + xc];
#pragma unroll
            for (int n = 0; n < 4; ++n)
                bF[n] = *(const bf16x8*)&lsB[(wc * 64 + n * 16 + lr) * 64 + xc];
#pragma unroll
            for (int m = 0; m < 4; ++m)
#pragma unroll
                for (int n = 0; n < 4; ++n)
                    acc[m][n] = __builtin_amdgcn_mfma_f32_16x16x32_bf16(aF[m], bF[n], acc[m][n], 0, 0, 0);
        }
    }

#pragma unroll
    for (int n = 0; n < 4; ++n) {
        const int col = n0col + wc * 64 + n * 16 + lr;
        const float bvv = bias[col];
#pragma unroll
        for (int m = 0; m < 4; ++m) {
            const int rowb = m0 + wr * 64 + m * 16 + kg * 4;
#pragma unroll
            for (int r = 0; r < 4; ++r) {
                const size_t idx = (size_t)(rowb + r) * N + col;
                float v = acc[m][n][r] + bvv;
                if (RESID) v += resid[idx];
                if (OUTF32) ((float*)Cv)[idx] = v;
                else        ((short*)Cv)[idx] = f2b(v);
            }
        }
    }
}

// Fused QKV GEMM, 1-D grid 1536 with XCD-bijective swizzle (verified r13).
__global__ __launch_bounds__(256)
void gemm_qkv(const short* __restrict__ A, const short* __restrict__ Wcat,
              const float* __restrict__ bq, const float* __restrict__ bk,
              const float* __restrict__ bv,
              short* __restrict__ Qw, short* __restrict__ Kw, short* __restrict__ Vw)
{
    __shared__ short lsA[128 * 64];
    __shared__ short lsB[128 * 64];
    const int L = blockIdx.x;                       // 0..1535
    const int wgid = (L & 7) * 192 + (L >> 3);      // bijective (1536 % 8 == 0)
    const int nb = wgid % 24;
    const int my = wgid / 24;
    const int tb = nb >> 3;
    const float* bias = (tb == 0) ? bq : (tb == 1) ? bk : bv;
    short* dst = (tb == 0) ? Qw : (tb == 1) ? Kw : Vw;
    gemm_core<false, false>(A + (size_t)my * 128 * 1024,
                            Wcat + (size_t)nb * 128 * 1024,
                            bias - (nb & 7) * 128,
                            nullptr, dst, my * 128, (nb & 7) * 128, 1024, 1024,
                            lsA, lsB);
}

// Out-projection GEMM, 1-D grid 512 with XCD-bijective swizzle (verified r13).
__global__ __launch_bounds__(256)
void gemm_out(const short* __restrict__ A, const short* __restrict__ Bw,
              const float* __restrict__ bias, const float* __restrict__ resid,
              float* __restrict__ C)
{
    __shared__ short lsA[128 * 64];
    __shared__ short lsB[128 * 64];
    const int L = blockIdx.x;                       // 0..511
    const int wgid = (L & 7) * 64 + (L >> 3);
    const int nb = wgid & 7, my = wgid >> 3;
    gemm_core<true, true>(A + (size_t)my * 128 * 1024,
                          Bw + (size_t)nb * 128 * 1024,
                          bias, resid, C, my * 128, nb * 128, 1024, 1024,
                          lsA, lsB);
}

// ---------------------------------------------------------------------------
// MFMA flash attention v10 = verified v9 + deeper chain overlap:
//  - lsP split per m (lsP[8][2][...]) -> no WAR serialization between phases
//  - both exp-pack chains run back-to-back while tr-reads drain; fence
//    (lgkmcnt(0)+sched_barrier, rule #18) moved to just before the single
//    36-MFMA PV cluster
//  - v_max3_f32 smax trees (T17)
// LDS 64 KiB -> still 2 blocks/CU (grid 512 = exactly 2/CU).
// ---------------------------------------------------------------------------
__global__ __launch_bounds__(512)
void attn_fwd(const short* __restrict__ Q, const short* __restrict__ K,
              const short* __restrict__ V, short* __restrict__ ctx)
{
    __shared__ short lsK[2][64 * 64];
    __shared__ short lsV[2][64 * 64];
    __shared__ short lsP[8][2][16 * 64];

    const float C1 = 0.18033688011112042f;   // 0.125 * log2(e)

    const int t = threadIdx.x, w = t >> 6, lane = t & 63;
    const int lr = lane & 15, kg = lane >> 4;
    const int bh = blockIdx.x;
    const size_t base = (size_t)(bh >> 4) * 2048 * 1024 + (size_t)(bh & 15) * 64;
    const short* Qg = Q + base;
    short* Og = ctx + base;
    const int q0 = blockIdx.y * 256 + w * 32;

    bf16x8 qB[2][2];
#pragma unroll
    for (int m = 0; m < 2; ++m)
#pragma unroll
        for (int ks = 0; ks < 2; ++ks)
            qB[m][ks] = *(const bf16x8*)(Qg + (size_t)(q0 + m * 16 + lr) * 1024 + ks * 32 + kg * 8);

    bf16x8 onesB;
#pragma unroll
    for (int j = 0; j < 8; ++j) onesB[j] = (short)0x3F80;

    const int rK  = t >> 3;
    const int cK  = (((t & 7) ^ (rK & 7))) * 8;
    const int kvV = (t & 127) >> 1;
    const int dV  = ((t >> 7) << 4) + (t & 1) * 8;
    const short* pK = K + base + (size_t)rK * 1024 + cK;
    const short* pV = V + base + (size_t)kvV * 1024 + dV;

    f32x4 o[2][4];
    f32x4 osum[2];
#pragma unroll
    for (int m = 0; m < 2; ++m) {
#pragma unroll
        for (int n = 0; n < 4; ++n) o[m][n] = zero4();
        osum[m] = zero4();
    }
    float mx[2] = {-1e30f, -1e30f};

    const int pmask = (lr & 7) << 3;

    async16(pK, &lsK[0][t * 8]);
    async16(pV, &lsV[0][t * 8]);

    int buf = 0;
    for (int it = 0; it < 32; ++it) {
        __syncthreads();
        if (it + 1 < 32) {
            pK += 65536; pV += 65536;
            async16(pK, &lsK[buf ^ 1][t * 8]);
            async16(pV, &lsV[buf ^ 1][t * 8]);
        }
        const short* cbK = lsK[buf];
        const short* cbV = lsV[buf];

        // ---- QK^T (swapped): s[m][cb][r] = S[q=m*16+lr][kv=cb*16+kg*4+r]
        f32x4 s[2][4];
        const int x0 = ((kg)     ^ (lr & 7)) * 8;
        const int x1 = ((4 + kg) ^ (lr & 7)) * 8;
        __builtin_amdgcn_s_setprio(1);
#pragma unroll
        for (int cb = 0; cb < 4; ++cb) {
            const bf16x8 kA0 = *(const bf16x8*)&cbK[(cb * 16 + lr) * 64 + x0];
            const bf16x8 kA1 = *(const bf16x8*)&cbK[(cb * 16 + lr) * 64 + x1];
#pragma unroll
            for (int m = 0; m < 2; ++m) {
                f32x4 a = __builtin_amdgcn_mfma_f32_16x16x32_bf16(kA0, qB[m][0], zero4(), 0, 0, 0);
                s[m][cb] = __builtin_amdgcn_mfma_f32_16x16x32_bf16(kA1, qB[m][1], a, 0, 0, 0);
            }
        }
        __builtin_amdgcn_s_setprio(0);

        // ---- V tr-reads issued EARLY: latency overlaps softmax + packs
        bf16x4 tv[4][4];
#pragma unroll
        for (int n = 0; n < 4; ++n) {
            const uint32_t a = lds_addr(&cbV[n * 1024 + kg * 128 + lr]);
            asm volatile(
                "ds_read_b64_tr_b16 %0, %4\n\t"
                "ds_read_b64_tr_b16 %1, %4 offset:128\n\t"
                "ds_read_b64_tr_b16 %2, %4 offset:1024\n\t"
                "ds_read_b64_tr_b16 %3, %4 offset:1152"
                : "=&v"(tv[n][0]), "=&v"(tv[n][1]), "=&v"(tv[n][2]), "=&v"(tv[n][3])
                : "v"(a));
        }

        // ---- tile max per q-row (v_max3 trees)
        float smax[2];
#pragma unroll
        for (int m = 0; m < 2; ++m) {
            const float t0 = max3f(s[m][0][0], s[m][0][1], s[m][0][2]);
            const float t1 = max3f(s[m][0][3], s[m][1][0], s[m][1][1]);
            const float t2 = max3f(s[m][1][2], s[m][1][3], s[m][2][0]);
            const float t3 = max3f(s[m][2][1], s[m][2][2], s[m][2][3]);
            const float t4 = max3f(s[m][3][0], s[m][3][1], s[m][3][2]);
            float e = fmaxf(max3f(t0, t1, t2), max3f(t3, t4, s[m][3][3]));
            e = fmaxf(e, __shfl_xor(e, 16));
            e = fmaxf(e, __shfl_xor(e, 32));
            smax[m] = e;
        }

        // ---- defer-max rescale (osum rescales with o; rare after warmup)
        if (!__all((smax[0] <= mx[0] + 64.f) && (smax[1] <= mx[1] + 64.f))) {
            float corrS[2];
#pragma unroll
            for (int m = 0; m < 2; ++m) {
                const float mnew = fmaxf(mx[m], smax[m]);
                corrS[m] = exp2fast((mx[m] - mnew) * C1);
                mx[m] = mnew;
            }
#pragma unroll
            for (int m = 0; m < 2; ++m) {
                f32x4 c;
#pragma unroll
                for (int r = 0; r < 4; ++r) c[r] = __shfl(corrS[m], kg * 4 + r);
#pragma unroll
                for (int n = 0; n < 4; ++n) {
                    o[m][n][0] *= c[0]; o[m][n][1] *= c[1];
                    o[m][n][2] *= c[2]; o[m][n][3] *= c[3];
                }
                osum[m][0] *= c[0]; osum[m][1] *= c[1];
                osum[m][2] *= c[2]; osum[m][3] *= c[3];
            }
        }

        // ---- both P packs back-to-back (separate lsP buffers per m)
#pragma unroll
        for (int m = 0; m < 2; ++m) {
            const float nm2 = mx[m] * C1;
            short* lsPm = lsP[w][m];
#pragma unroll
            for (int cb = 0; cb < 4; ++cb) {
                const float p0 = exp2fast(fmaf(s[m][cb][0], C1, -nm2));
                const float p1 = exp2fast(fmaf(s[m][cb][1], C1, -nm2));
                const float p2 = exp2fast(fmaf(s[m][cb][2], C1, -nm2));
                const float p3 = exp2fast(fmaf(s[m][cb][3], C1, -nm2));
                const int c0i = (cb * 16 + kg * 4) ^ pmask;
                *(uint32_t*)&lsPm[lr * 64 + c0i]     = cvtpk(p0, p1);
                *(uint32_t*)&lsPm[lr * 64 + c0i + 2] = cvtpk(p2, p3);
            }
        }

        // ---- both pA reads
        bf16x8 pA[2][2];
#pragma unroll
        for (int m = 0; m < 2; ++m)
#pragma unroll
            for (int kh = 0; kh < 2; ++kh)
                pA[m][kh] = *(const bf16x8*)&lsP[w][m][lr * 64 + ((kh * 32 + kg * 8) ^ pmask)];

        // ---- single fence for tr-reads + pA, right before the MFMA cluster
        asm volatile("s_waitcnt lgkmcnt(0)" ::: "memory");
        __builtin_amdgcn_sched_barrier(0);

        // ---- one 36-MFMA cluster: PV(m0)+PV(m1)+ones-sums
        __builtin_amdgcn_s_setprio(1);
#pragma unroll
        for (int n = 0; n < 4; ++n) {
#pragma unroll
            for (int kh = 0; kh < 2; ++kh) {
                const bf16x8 vB = __builtin_shufflevector(tv[n][kh * 2], tv[n][kh * 2 + 1],
                                                          0, 1, 2, 3, 4, 5, 6, 7);
#pragma unroll
                for (int m = 0; m < 2; ++m)
                    o[m][n] = __builtin_amdgcn_mfma_f32_16x16x32_bf16(pA[m][kh], vB, o[m][n], 0, 0, 0);
            }
        }
#pragma unroll
        for (int m = 0; m < 2; ++m) {
            osum[m] = __builtin_amdgcn_mfma_f32_16x16x32_bf16(pA[m][0], onesB, osum[m], 0, 0, 0);
            osum[m] = __builtin_amdgcn_mfma_f32_16x16x32_bf16(pA[m][1], onesB, osum[m], 0, 0, 0);
        }
        __builtin_amdgcn_s_setprio(0);
        buf ^= 1;
    }

    // ---- epilogue: normalize; osum layout matches output rows exactly
#pragma unroll
    for (int m = 0; m < 2; ++m) {
        f32x4 inv;
#pragma unroll
        for (int r = 0; r < 4; ++r) inv[r] = 1.0f / osum[m][r];
#pragma unroll
        for (int n = 0; n < 4; ++n)
#pragma unroll
            for (int r = 0; r < 4; ++r) {
                const int row = q0 + m * 16 + kg * 4 + r;
                Og[(size_t)row * 1024 + n * 16 + lr] = f2b(o[m][n][r] * inv[r]);
            }
    }
}

// ---------------------------------------------------------------------------
// In-place rowwise LayerNorm on d_out (fp32) (unchanged, verified).
// ---------------------------------------------------------------------------
__global__ __launch_bounds__(256)
void ln_inplace(float* __restrict__ io, const float* __restrict__ gamma,
                const float* __restrict__ beta)
{
    __shared__ float redS[4];
    __shared__ float redQ[4];
    const int t = threadIdx.x, wave = t >> 6, lane = t & 63;
    const size_t rb = (size_t)blockIdx.x * 1024;

    float4 v4 = *(const float4*)&io[rb + t * 4];
    float v[4] = {v4.x, v4.y, v4.z, v4.w};

    float s = 0.f, sq = 0.f;
#pragma unroll
    for (int j = 0; j < 4; ++j) { s += v[j]; sq += v[j] * v[j]; }
#pragma unroll
    for (int off = 32; off; off >>= 1) {
        s  += __shfl_xor(s, off);
        sq += __shfl_xor(sq, off);
    }
    if (lane == 0) { redS[wave] = s; redQ[wave] = sq; }
    __syncthreads();
    const float mean = (redS[0] + redS[1] + redS[2] + redS[3]) * (1.0f / 1024.0f);
    const float ex2  = (redQ[0] + redQ[1] + redQ[2] + redQ[3]) * (1.0f / 1024.0f);
    const float var  = fmaxf(ex2 - mean * mean, 0.f);
    const float inv  = rsqrtf(var + 1e-5f);

    float4 o4;
    o4.x = (v[0] - mean) * inv * gamma[t * 4 + 0] + beta[t * 4 + 0];
    o4.y = (v[1] - mean) * inv * gamma[t * 4 + 1] + beta[t * 4 + 1];
    o4.z = (v[2] - mean) * inv * gamma[t * 4 + 2] + beta[t * 4 + 2];
    o4.w = (v[3] - mean) * inv * gamma[t * 4 + 3] + beta[t * 4 + 3];
    *(float4*)&io[rb + t * 4] = o4;
}

// ---------------------------------------------------------------------------
extern "C" void kernel_launch(void* const* d_in, const int* in_sizes, int n_in,
                              void* d_out, int out_size, void* d_ws, size_t ws_size,
                              hipStream_t stream)
{
    const float* x  = (const float*)d_in[0];
    const float* Wq = (const float*)d_in[1];
    const float* bq = (const float*)d_in[2];
    const float* Wk = (const float*)d_in[3];
    const float* bk = (const float*)d_in[4];
    const float* Wv = (const float*)d_in[5];
    const float* bv = (const float*)d_in[6];
    const float* Wo = (const float*)d_in[7];
    const float* bo = (const float*)d_in[8];
    const float* gamma = (const float*)d_in[9];
    const float* beta  = (const float*)d_in[10];

    const size_t NX = (size_t)8192 * 1024;
    const size_t NW = (size_t)1024 * 1024;

    short* xb  = (short*)d_ws;
    short* Wqb = xb + NX;          // [Wq;Wk;Wv] contiguous for fused GEMM
    short* Wkb = Wqb + NW;
    short* Wvb = Wkb + NW;
    short* Wob = Wvb + NW;
    short* Qw  = Wob + NW;
    short* Kw  = Qw + NX;
    short* Vw  = Kw + NX;
    short* Cw  = Vw + NX;
    float* out = (float*)d_out;

    cvt5<<<dim3(12288), dim3(256), 0, stream>>>(x, Wq, Wk, Wv, Wo, xb, Wqb, Wkb, Wvb, Wob);
    gemm_qkv<<<dim3(1536), dim3(256), 0, stream>>>(xb, Wqb, bq, bk, bv, Qw, Kw, Vw);
    attn_fwd<<<dim3(64, 8), dim3(512), 0, stream>>>(Qw, Kw, Vw, Cw);
    gemm_out<<<dim3(512), dim3(256), 0, stream>>>(Cw, Wob, bo, x, out);
    ln_inplace<<<dim3(8192), dim3(256), 0, stream>>>(out, gamma, beta);
}